// Round 10
// baseline (74.614 us; speedup 1.0000x reference)
//
#include <hip/hip_runtime.h>
#include <math.h>

#define T 34
#define V 14
#define NT 256
#define NBLK 1088
#define NWAVES 4352            // NBLK*4 = 17*256 -> tile stride preserves per-lane t-invariance
#define NPAIRS 4               // 8 tiles/wave as 4 pairs
#define LIM (65536 * 34)

typedef float f32x4 __attribute__((ext_vector_type(4)));

__global__ __launch_bounds__(NT, 4) void micro_fused(
    const int* __restrict__ idx, float* __restrict__ out,
    const float* __restrict__ p_tokA, const float* __restrict__ p_tokStart,
    const float* __restrict__ p_tokStride, const float* __restrict__ p_spAmp,
    const float* __restrict__ p_spPhase, const float* __restrict__ p_spSlope,
    const float* __restrict__ p_spOffset, const float* __restrict__ norm_w,
    const float* __restrict__ q_w, const float* __restrict__ q_phase,
    const float* __restrict__ out_A, const float* __restrict__ out_B,
    const float* __restrict__ fc1_w, const float* __restrict__ fc2_w,
    const float* __restrict__ head_w)
{
    __shared__ float G_lds[V * 35];        // 1960 B
    __shared__ float TE_lds[V * 2];        // 112 B
    __shared__ float POS_lds[T * 3];       // 408 B
    __shared__ float gbW[4][2][208];       // per-wave double-buffered g staging (6.6 KB)
    __shared__ float stageW[4][2][896];    // per-wave double-buffered logit staging (28.7 KB)
    // total ~37.8 KB -> 4 blocks/CU

    const int tid = threadIdx.x;
    const int w = tid >> 6, lane = tid & 63;
    const int wid = blockIdx.x * 4 + w;

    // setup scratch aliases the stage region (block-wide, pre-barrier only)
    float* sA = &stageW[0][0][0];          // raw scores A[34][35]
    float* sK = sA + 1200;                 // K[34][5]
    float* sQ = sA + 1370;                 // Q[34][5]

    // ---------- setup phase 1: TE, POS, K, Q ----------
    if (tid < V) {
        float ang = p_tokStart[0] + (float)tid * p_tokStride[0];
        TE_lds[2 * tid]     = p_tokA[0] * cosf(ang);
        TE_lds[2 * tid + 1] = p_tokA[0] * sinf(ang);
    }
    if (tid < T) {
        float th = (float)tid * 0.62831853071795864769f + p_spPhase[0]; // 2*pi/10
        float p0 = p_spAmp[0] * cosf(th), p1 = p_spAmp[0] * sinf(th);
        float p2 = p_spSlope[0] * (float)tid + p_spOffset[0];
        POS_lds[3 * tid] = p0; POS_lds[3 * tid + 1] = p1; POS_lds[3 * tid + 2] = p2;
        float kk[5];
        #pragma unroll
        for (int i = 0; i < 5; ++i)
            kk[i] = p0 * q_w[3 * i] + p1 * q_w[3 * i + 1] + p2 * q_w[3 * i + 2];
        float cc = cosf(q_phase[0]), ss = sinf(q_phase[0]);
        #pragma unroll
        for (int i = 0; i < 5; ++i) sK[tid * 5 + i] = kk[i];
        sQ[tid * 5 + 0] = cc * kk[0] - ss * kk[1];
        sQ[tid * 5 + 1] = ss * kk[0] + cc * kk[1];
        sQ[tid * 5 + 2] = kk[2]; sQ[tid * 5 + 3] = kk[3]; sQ[tid * 5 + 4] = kk[4];
    }
    __syncthreads();

    // ---------- setup phase 2: raw scores (0 above diag) + G table ----------
    for (int e = tid; e < T * T; e += NT) {
        unsigned tt = (unsigned)e / (unsigned)T;
        unsigned s  = (unsigned)e - tt * T;
        float d = 0.f;
        #pragma unroll
        for (int i = 0; i < 5; ++i) d += sQ[tt * 5 + i] * sK[s * 5 + i];
        sA[tt * 35 + s] = (s <= tt) ? d * 0.44721359549995793928f : 0.f;
    }
    for (int e = tid; e < V * 35; e += NT) {
        int v = e / 35, s = e - v * 35;
        float g = 0.f;
        if (s < T) {
            float x0 = TE_lds[2*v], x1 = TE_lds[2*v+1];
            float x2 = POS_lds[3*s], x3 = POS_lds[3*s+1], x4 = POS_lds[3*s+2];
            float ms = (x0*x0 + x1*x1 + x2*x2 + x3*x3 + x4*x4) * 0.2f;
            float r = rsqrtf(ms + 1e-5f);
            g = (x0 * norm_w[0] * out_A[0] + x1 * norm_w[1] * out_A[1]
               + x2 * norm_w[2] * out_A[2] + x3 * norm_w[3] * out_A[3]
               + x4 * norm_w[4] * out_A[4]) * r;
        }
        G_lds[e] = g;
    }
    __syncthreads();

    // ---------- per-lane: A-row softmax in registers ----------
    const int t = (wid * 64 + lane) % T;   // invariant across this wave's tiles
    float A[T];
    #pragma unroll
    for (int s = 0; s < T; ++s) A[s] = sA[t * 35 + s];
    {
        float mx = -1e30f;
        #pragma unroll
        for (int s = 0; s < T; ++s) if (s <= t) mx = fmaxf(mx, A[s]);
        float sum = 0.f;
        #pragma unroll
        for (int s = 0; s < T; ++s) {
            float e2 = (s <= t) ? expf(A[s] - mx) : 0.f;
            A[s] = e2;
            sum += e2;
        }
        float inv = 1.f / sum;
        #pragma unroll
        for (int s = 0; s < T; ++s) A[s] *= inv;
    }
    const float ps0 = POS_lds[3*t], ps1 = POS_lds[3*t+1], ps2 = POS_lds[3*t+2];
    float te0[V], te1[V];
    #pragma unroll
    for (int v = 0; v < V; ++v) { te0[v] = TE_lds[2*v]; te1[v] = TE_lds[2*v+1]; }
    __syncthreads();   // last barrier: stage region now owned per-wave

    // uniform weights -> scalar loads / SGPRs
    const float nw0 = norm_w[0], nw1 = norm_w[1], nw2 = norm_w[2], nw3 = norm_w[3], nw4 = norm_w[4];
    const float oB0 = out_B[0], oB1 = out_B[1], oB2 = out_B[2], oB3 = out_B[3], oB4 = out_B[4];
    float w1[2][5], hw[2][5], w20[5], w21[5];
    #pragma unroll
    for (int j = 0; j < 2; ++j)
        #pragma unroll
        for (int d = 0; d < 5; ++d) { w1[j][d] = fc1_w[j*5+d]; hw[j][d] = head_w[j*5+d]; }
    #pragma unroll
    for (int d = 0; d < 5; ++d) { w20[d] = fc2_w[2*d]; w21[d] = fc2_w[2*d+1]; }

    // staging-lane invariants
    const int s_a = (lane < T) ? lane : lane - T;
    const int i2 = lane + 64;
    const int s_b = (i2 < 68) ? i2 - 34 : i2 - 68;
    const bool act2 = (i2 < 102);

    auto loadTok = [&](int p, int& t0A, int& t1A, int& toA, int& t0B, int& t1B, int& toB) {
        int tA = wid + (2 * p)     * NWAVES;
        int tB = wid + (2 * p + 1) * NWAVES;
        int bA = (tA * 64) / T, bB = (tB * 64) / T;
        t0A = idx[bA * T + lane];
        t1A = idx[min(bA * T + lane + 64, LIM - 1)];
        toA = idx[tA * 64 + lane];
        t0B = idx[bB * T + lane];
        t1B = idx[min(bB * T + lane + 64, LIM - 1)];
        toB = idx[tB * 64 + lane];
    };
    auto stageP = [&](float* dst, int t0A, int t1A, int t0B, int t1B) {
        dst[lane] = G_lds[t0A * 35 + s_a];
        if (act2) dst[i2] = G_lds[t1A * 35 + s_b];
        dst[104 + lane] = G_lds[t0B * 35 + s_a];
        if (act2) dst[104 + i2] = G_lds[t1B * 35 + s_b];
    };
    auto dot = [&](const float* gbT, int rbase) -> float {
        float acc0 = 0.f, acc1 = 0.f;
        const float2* gbp = reinterpret_cast<const float2*>(gbT + rbase);
        #pragma unroll
        for (int s = 0; s < 17; ++s) {
            float2 gg = gbp[s];
            acc0 = fmaf(A[2*s],   gg.x, acc0);
            acc1 = fmaf(A[2*s+1], gg.y, acc1);
        }
        return acc0 + acc1;
    };
    auto epi = [&](float* stg, int curtok, float acc) {
        float2 te = *reinterpret_cast<const float2*>(&TE_lds[curtok * 2]);
        float x0 = te.x + acc * oB0;
        float x1 = te.y + acc * oB1;
        float x2 = ps0 + acc * oB2;
        float x3 = ps1 + acc * oB3;
        float x4 = ps2 + acc * oB4;

        float ms = (x0*x0 + x1*x1 + x2*x2 + x3*x3 + x4*x4) * 0.2f;
        float rr = rsqrtf(ms + 1e-5f);
        float h0 = x0*rr*nw0, h1 = x1*rr*nw1, h2 = x2*rr*nw2, h3 = x3*rr*nw3, h4 = x4*rr*nw4;
        float f0 = fmaxf(0.f, h0*w1[0][0] + h1*w1[0][1] + h2*w1[0][2] + h3*w1[0][3] + h4*w1[0][4]);
        float f1 = fmaxf(0.f, h0*w1[1][0] + h1*w1[1][1] + h2*w1[1][2] + h3*w1[1][3] + h4*w1[1][4]);
        x0 += f0*w20[0] + f1*w21[0];
        x1 += f0*w20[1] + f1*w21[1];
        x2 += f0*w20[2] + f1*w21[2];
        x3 += f0*w20[3] + f1*w21[3];
        x4 += f0*w20[4] + f1*w21[4];

        ms = (x0*x0 + x1*x1 + x2*x2 + x3*x3 + x4*x4) * 0.2f;
        rr = rsqrtf(ms + 1e-5f);
        h0 = x0*rr*nw0; h1 = x1*rr*nw1; h2 = x2*rr*nw2; h3 = x3*rr*nw3; h4 = x4*rr*nw4;
        float p0 = h0*hw[0][0] + h1*hw[0][1] + h2*hw[0][2] + h3*hw[0][3] + h4*hw[0][4];
        float p1 = h0*hw[1][0] + h1*hw[1][1] + h2*hw[1][2] + h3*hw[1][3] + h4*hw[1][4];

        float2* stg2 = reinterpret_cast<float2*>(stg);
        #pragma unroll
        for (int j = 0; j < 7; ++j) {
            float2 o2;
            o2.x = p0 * te0[2*j]   + p1 * te1[2*j];
            o2.y = p0 * te0[2*j+1] + p1 * te1[2*j+1];
            stg2[lane * 7 + j] = o2;
        }
    };
    auto copyout = [&](int tile, const float* stg) {
        const f32x4* st4 = reinterpret_cast<const f32x4*>(stg);
        f32x4* outp = reinterpret_cast<f32x4*>(out) + (size_t)tile * 224;
        __builtin_nontemporal_store(st4[lane],       outp + lane);
        __builtin_nontemporal_store(st4[lane + 64],  outp + lane + 64);
        __builtin_nontemporal_store(st4[lane + 128], outp + lane + 128);
        if (lane < 32)
            __builtin_nontemporal_store(st4[lane + 192], outp + lane + 192);
    };

    // ---------------- main loop: gb dbuf + logit-stage dbuf (copyout lags 1 tile) ----------------
    int c_t0A, c_t1A, c_toA, c_t0B, c_t1B, c_toB;
    int n_t0A, n_t1A, n_toA, n_t0B, n_t1B, n_toB;
    loadTok(0, c_t0A, c_t1A, c_toA, c_t0B, c_t1B, c_toB);
    stageP(gbW[w][0], c_t0A, c_t1A, c_t0B, c_t1B);
    loadTok(1, n_t0A, n_t1A, n_toA, n_t0B, n_t1B, n_toB);
    int curToA = c_toA, curToB = c_toB;

    #pragma unroll
    for (int it = 0; it < NPAIRS; ++it) {
        float* g = gbW[w][it & 1];
        const int tX = wid + (2 * it)     * NWAVES;   // even tile -> stage buf 0
        const int tY = wid + (2 * it + 1) * NWAVES;   // odd tile  -> stage buf 1
        const int rbX = ((tX * 64 + lane) / T - (tX * 64) / T) * T;
        const int rbY = ((tY * 64 + lane) / T - (tY * 64) / T) * T;

        float accX = dot(g,       rbX);
        float accY = dot(g + 104, rbY);
        const int ctX = curToA, ctY = curToB;

        // stage next pair's gb into the alternate buffer; prefetch tokens
        if (it < NPAIRS - 1) {
            stageP(gbW[w][(it + 1) & 1], n_t0A, n_t1A, n_t0B, n_t1B);
            curToA = n_toA; curToB = n_toB;
            if (it < NPAIRS - 2)
                loadTok(it + 2, n_t0A, n_t1A, n_toA, n_t0B, n_t1B, n_toB);
        }

        epi(stageW[w][0], ctX, accX);                       // write tile 2it
        if (it > 0) copyout(tY - 2 * NWAVES, stageW[w][1]); // drain tile 2it-1
        epi(stageW[w][1], ctY, accY);                       // write tile 2it+1
        copyout(tX, stageW[w][0]);                          // drain tile 2it
    }
    copyout(wid + 7 * NWAVES, stageW[w][1]);                // tail: tile 7
}

extern "C" void kernel_launch(void* const* d_in, const int* in_sizes, int n_in,
                              void* d_out, int out_size, void* d_ws, size_t ws_size,
                              hipStream_t stream) {
    const int*   idx        = (const int*)  d_in[0];
    const float* tok_A      = (const float*)d_in[1];
    const float* tok_start  = (const float*)d_in[2];
    const float* tok_stride = (const float*)d_in[3];
    const float* sp_amp     = (const float*)d_in[4];
    const float* sp_phase   = (const float*)d_in[5];
    const float* sp_slope   = (const float*)d_in[6];
    const float* sp_offset  = (const float*)d_in[7];
    const float* norm_w     = (const float*)d_in[8];
    const float* q_w        = (const float*)d_in[9];
    const float* q_phase    = (const float*)d_in[10];
    const float* out_A      = (const float*)d_in[11];
    const float* out_B      = (const float*)d_in[12];
    const float* fc1_w      = (const float*)d_in[13];
    const float* fc2_w      = (const float*)d_in[14];
    const float* head_w     = (const float*)d_in[15];
    float* out = (float*)d_out;

    micro_fused<<<NBLK, NT, 0, stream>>>(idx, out, tok_A, tok_start, tok_stride,
                                         sp_amp, sp_phase, sp_slope, sp_offset,
                                         norm_w, q_w, q_phase, out_A, out_B,
                                         fc1_w, fc2_w, head_w);
}

// Round 11
// 36.073 us; speedup vs baseline: 2.0684x; 2.0684x over previous
//
#include <hip/hip_runtime.h>
#include <math.h>

#define T 34
#define V 14
#define NT 256
#define NBLK 1088
#define NWAVES 4352            // NBLK*4; 4352 = 17*256 -> tile stride preserves t-invariance
#define KTILES 8               // tiles per wave; NWAVES*KTILES*64 = 65536*34
#define NPAIRS 4
#define LIM (65536 * 34)

typedef float f32x4 __attribute__((ext_vector_type(4)));

__attribute__((amdgpu_waves_per_eu(4, 4)))   // pin 4 waves/EU -> 128 VGPR budget, no spills
__global__ __launch_bounds__(NT) void micro_fused(
    const int* __restrict__ idx, float* __restrict__ out,
    const float* __restrict__ p_tokA, const float* __restrict__ p_tokStart,
    const float* __restrict__ p_tokStride, const float* __restrict__ p_spAmp,
    const float* __restrict__ p_spPhase, const float* __restrict__ p_spSlope,
    const float* __restrict__ p_spOffset, const float* __restrict__ norm_w,
    const float* __restrict__ q_w, const float* __restrict__ q_phase,
    const float* __restrict__ out_A, const float* __restrict__ out_B,
    const float* __restrict__ fc1_w, const float* __restrict__ fc2_w,
    const float* __restrict__ head_w)
{
    __shared__ float G_lds[V * 35];      // 1960 B
    __shared__ float TE_lds[V * 2];      // 112 B
    __shared__ float POS_lds[T * 3];     // 408 B
    __shared__ float gbW[4][2][104];     // 3328 B
    __shared__ float stageAll[4 * 896];  // 14336 B; setup scratch then logit stage
    // total ~19.7 KB

    const int tid = threadIdx.x;
    const int w = tid >> 6, lane = tid & 63;
    const int wid = blockIdx.x * 4 + w;

    float* sA = stageAll;            // raw scores A[34][35] during setup
    float* sK = stageAll + 1200;     // K[34][5]
    float* sQ = stageAll + 1370;     // Q[34][5]

    // ---------- setup phase 1: TE, POS, K, Q (parallel) ----------
    if (tid < V) {
        float ang = p_tokStart[0] + (float)tid * p_tokStride[0];
        TE_lds[2 * tid]     = p_tokA[0] * cosf(ang);
        TE_lds[2 * tid + 1] = p_tokA[0] * sinf(ang);
    }
    if (tid < T) {
        float th = (float)tid * 0.62831853071795864769f + p_spPhase[0]; // 2*pi/10
        float p0 = p_spAmp[0] * cosf(th), p1 = p_spAmp[0] * sinf(th);
        float p2 = p_spSlope[0] * (float)tid + p_spOffset[0];
        POS_lds[3 * tid] = p0; POS_lds[3 * tid + 1] = p1; POS_lds[3 * tid + 2] = p2;
        float kk[5];
        #pragma unroll
        for (int i = 0; i < 5; ++i)
            kk[i] = p0 * q_w[3 * i] + p1 * q_w[3 * i + 1] + p2 * q_w[3 * i + 2];
        float cc = cosf(q_phase[0]), ss = sinf(q_phase[0]);
        #pragma unroll
        for (int i = 0; i < 5; ++i) sK[tid * 5 + i] = kk[i];
        sQ[tid * 5 + 0] = cc * kk[0] - ss * kk[1];
        sQ[tid * 5 + 1] = ss * kk[0] + cc * kk[1];
        sQ[tid * 5 + 2] = kk[2]; sQ[tid * 5 + 3] = kk[3]; sQ[tid * 5 + 4] = kk[4];
    }
    __syncthreads();

    // ---------- setup phase 2: raw scores (0 above diag) + G table ----------
    for (int e = tid; e < T * T; e += NT) {
        unsigned tt = (unsigned)e / (unsigned)T;
        unsigned s  = (unsigned)e - tt * T;
        float d = 0.f;
        #pragma unroll
        for (int i = 0; i < 5; ++i) d += sQ[tt * 5 + i] * sK[s * 5 + i];
        sA[tt * 35 + s] = (s <= tt) ? d * 0.44721359549995793928f : 0.f;
    }
    for (int e = tid; e < V * 35; e += NT) {
        int v = e / 35, s = e - v * 35;
        float g = 0.f;
        if (s < T) {
            float x0 = TE_lds[2*v], x1 = TE_lds[2*v+1];
            float x2 = POS_lds[3*s], x3 = POS_lds[3*s+1], x4 = POS_lds[3*s+2];
            float ms = (x0*x0 + x1*x1 + x2*x2 + x3*x3 + x4*x4) * 0.2f;
            float r = rsqrtf(ms + 1e-5f);
            g = (x0 * norm_w[0] * out_A[0] + x1 * norm_w[1] * out_A[1]
               + x2 * norm_w[2] * out_A[2] + x3 * norm_w[3] * out_A[3]
               + x4 * norm_w[4] * out_A[4]) * r;
        }
        G_lds[e] = g;
    }
    __syncthreads();

    // ---------- per-lane invariants: load raw score row, softmax in registers ----------
    const int t = (wid * 64 + lane) % T;   // invariant across this wave's tiles
    float A[T];
    #pragma unroll
    for (int s = 0; s < T; ++s) A[s] = sA[t * 35 + s];
    {
        float mx = -1e30f;
        #pragma unroll
        for (int s = 0; s < T; ++s) if (s <= t) mx = fmaxf(mx, A[s]);
        float sum = 0.f;
        #pragma unroll
        for (int s = 0; s < T; ++s) {
            float e2 = (s <= t) ? expf(A[s] - mx) : 0.f;
            A[s] = e2;
            sum += e2;
        }
        float inv = 1.f / sum;
        #pragma unroll
        for (int s = 0; s < T; ++s) A[s] *= inv;
    }
    const float ps0 = POS_lds[3*t], ps1 = POS_lds[3*t+1], ps2 = POS_lds[3*t+2];
    float te0[V], te1[V];
    #pragma unroll
    for (int v = 0; v < V; ++v) { te0[v] = TE_lds[2*v]; te1[v] = TE_lds[2*v+1]; }
    __syncthreads();   // last barrier: stageAll now reusable as logit stage

    // uniform weights: literal-indexed -> scalar loads / SGPRs
    const float nw0 = norm_w[0], nw1 = norm_w[1], nw2 = norm_w[2], nw3 = norm_w[3], nw4 = norm_w[4];
    const float oB0 = out_B[0], oB1 = out_B[1], oB2 = out_B[2], oB3 = out_B[3], oB4 = out_B[4];
    float w1[2][5], hw[2][5], w20[5], w21[5];
    #pragma unroll
    for (int j = 0; j < 2; ++j)
        #pragma unroll
        for (int d = 0; d < 5; ++d) { w1[j][d] = fc1_w[j*5+d]; hw[j][d] = head_w[j*5+d]; }
    #pragma unroll
    for (int d = 0; d < 5; ++d) { w20[d] = fc2_w[2*d]; w21[d] = fc2_w[2*d+1]; }

    // staging-lane invariants
    const int s_a = (lane < T) ? lane : lane - T;
    const int i2 = lane + 64;
    const int s_b = (i2 < 68) ? i2 - 34 : i2 - 68;
    const bool act2 = (i2 < 102);

    float* gbA = gbW[w][0];
    float* gbB = gbW[w][1];
    float* stg = stageAll + w * 896;
    float2* stg2 = reinterpret_cast<float2*>(stg);
    const f32x4* st4 = reinterpret_cast<const f32x4*>(stg);

    auto computeItem = [&](int tile, int rbase, int curtok, const float* gbT) {
        float acc0 = 0.f, acc1 = 0.f;
        const float2* gbp = reinterpret_cast<const float2*>(gbT + rbase);
        #pragma unroll
        for (int s = 0; s < 17; ++s) {
            float2 gg = gbp[s];
            acc0 = fmaf(A[2*s],   gg.x, acc0);
            acc1 = fmaf(A[2*s+1], gg.y, acc1);
        }
        float acc = acc0 + acc1;

        float2 te = *reinterpret_cast<const float2*>(&TE_lds[curtok * 2]);
        float x0 = te.x + acc * oB0;
        float x1 = te.y + acc * oB1;
        float x2 = ps0 + acc * oB2;
        float x3 = ps1 + acc * oB3;
        float x4 = ps2 + acc * oB4;

        float ms = (x0*x0 + x1*x1 + x2*x2 + x3*x3 + x4*x4) * 0.2f;
        float rr = rsqrtf(ms + 1e-5f);
        float h0 = x0*rr*nw0, h1 = x1*rr*nw1, h2 = x2*rr*nw2, h3 = x3*rr*nw3, h4 = x4*rr*nw4;
        float f0 = fmaxf(0.f, h0*w1[0][0] + h1*w1[0][1] + h2*w1[0][2] + h3*w1[0][3] + h4*w1[0][4]);
        float f1 = fmaxf(0.f, h0*w1[1][0] + h1*w1[1][1] + h2*w1[1][2] + h3*w1[1][3] + h4*w1[1][4]);
        x0 += f0*w20[0] + f1*w21[0];
        x1 += f0*w20[1] + f1*w21[1];
        x2 += f0*w20[2] + f1*w21[2];
        x3 += f0*w20[3] + f1*w21[3];
        x4 += f0*w20[4] + f1*w21[4];

        ms = (x0*x0 + x1*x1 + x2*x2 + x3*x3 + x4*x4) * 0.2f;
        rr = rsqrtf(ms + 1e-5f);
        h0 = x0*rr*nw0; h1 = x1*rr*nw1; h2 = x2*rr*nw2; h3 = x3*rr*nw3; h4 = x4*rr*nw4;
        float p0 = h0*hw[0][0] + h1*hw[0][1] + h2*hw[0][2] + h3*hw[0][3] + h4*hw[0][4];
        float p1 = h0*hw[1][0] + h1*hw[1][1] + h2*hw[1][2] + h3*hw[1][3] + h4*hw[1][4];

        #pragma unroll
        for (int j = 0; j < 7; ++j) {
            float2 o2;
            o2.x = p0 * te0[2*j]   + p1 * te1[2*j];
            o2.y = p0 * te0[2*j+1] + p1 * te1[2*j+1];
            stg2[lane * 7 + j] = o2;
        }
        // same-wave LDS ordering: reads below see the writes above
        f32x4* outp = reinterpret_cast<f32x4*>(out) + (size_t)tile * 224;
        __builtin_nontemporal_store(st4[lane],       outp + lane);
        __builtin_nontemporal_store(st4[lane + 64],  outp + lane + 64);
        __builtin_nontemporal_store(st4[lane + 128], outp + lane + 128);
        if (lane < 32)
            __builtin_nontemporal_store(st4[lane + 192], outp + lane + 192);
    };

    // ---- 8 tiles per wave, processed as 4 pairs (2-way ILP, cross-pair prefetch) ----
    int tileA = wid, tileB = wid + NWAVES;
    int b0A = (tileA * 64) / T, b0B = (tileB * 64) / T;
    int tk0A = idx[b0A * T + lane];
    int tk1A = idx[min(b0A * T + lane + 64, LIM - 1)];
    int tkoA = idx[tileA * 64 + lane];
    int tk0B = idx[b0B * T + lane];
    int tk1B = idx[min(b0B * T + lane + 64, LIM - 1)];
    int tkoB = idx[tileB * 64 + lane];

    #pragma unroll
    for (int it = 0; it < NPAIRS; ++it) {
        gbA[lane] = G_lds[tk0A * 35 + s_a];
        if (act2) gbA[i2] = G_lds[tk1A * 35 + s_b];
        gbB[lane] = G_lds[tk0B * 35 + s_a];
        if (act2) gbB[i2] = G_lds[tk1B * 35 + s_b];

        const int rbA = ((tileA * 64 + lane) / T - b0A) * T;
        const int rbB = ((tileB * 64 + lane) / T - b0B) * T;
        const int ctA = tkoA, ctB = tkoB;
        const int tA = tileA, tB = tileB;

        if (it < NPAIRS - 1) {
            tileA += 2 * NWAVES; tileB += 2 * NWAVES;
            b0A = (tileA * 64) / T; b0B = (tileB * 64) / T;
            tk0A = idx[b0A * T + lane];
            tk1A = idx[min(b0A * T + lane + 64, LIM - 1)];
            tkoA = idx[tileA * 64 + lane];
            tk0B = idx[b0B * T + lane];
            tk1B = idx[min(b0B * T + lane + 64, LIM - 1)];
            tkoB = idx[tileB * 64 + lane];
        }

        computeItem(tA, rbA, ctA, gbA);
        computeItem(tB, rbB, ctB, gbB);
    }
}

extern "C" void kernel_launch(void* const* d_in, const int* in_sizes, int n_in,
                              void* d_out, int out_size, void* d_ws, size_t ws_size,
                              hipStream_t stream) {
    const int*   idx        = (const int*)  d_in[0];
    const float* tok_A      = (const float*)d_in[1];
    const float* tok_start  = (const float*)d_in[2];
    const float* tok_stride = (const float*)d_in[3];
    const float* sp_amp     = (const float*)d_in[4];
    const float* sp_phase   = (const float*)d_in[5];
    const float* sp_slope   = (const float*)d_in[6];
    const float* sp_offset  = (const float*)d_in[7];
    const float* norm_w     = (const float*)d_in[8];
    const float* q_w        = (const float*)d_in[9];
    const float* q_phase    = (const float*)d_in[10];
    const float* out_A      = (const float*)d_in[11];
    const float* out_B      = (const float*)d_in[12];
    const float* fc1_w      = (const float*)d_in[13];
    const float* fc2_w      = (const float*)d_in[14];
    const float* head_w     = (const float*)d_in[15];
    float* out = (float*)d_out;

    micro_fused<<<NBLK, NT, 0, stream>>>(idx, out, tok_A, tok_start, tok_stride,
                                         sp_amp, sp_phase, sp_slope, sp_offset,
                                         norm_w, q_w, q_phase, out_A, out_B,
                                         fc1_w, fc2_w, head_w);
}